// Round 2
// baseline (87.352 us; speedup 1.0000x reference)
//
#include <hip/hip_runtime.h>

// B=8192, J=17, F=128. f32 in/out.
// ws layout (float index):
//   [0, 16384)        : 64 slots x (128 sum + 128 sumsq) BN partials (memset 0 per launch)
//   [16384, 16640)    : stats: scale[128], shift[128]
//   [16640, 16929)    : off_sym[17*17]
//   [16929, 16946)    : diag[17]
//   [16960, +16384)   : W^T bf16 [256 cols][128 k]  (64KB)

#define NSLOT 64
#define OFF_PART   0
#define OFF_STATS  16384
#define OFF_OFFSYM 16640
#define OFF_DIAG   16929
#define OFF_WBT    16960

typedef __attribute__((ext_vector_type(8))) short bf16x8;
typedef __attribute__((ext_vector_type(4))) short bf16x4;
typedef __attribute__((ext_vector_type(4))) float f32x4;

__device__ __forceinline__ short f2bf(float f) {
    unsigned u = __float_as_uint(f);
    u += 0x7FFFu + ((u >> 16) & 1u);   // round-to-nearest-even
    return (short)(u >> 16);
}
__device__ __forceinline__ float bf2f(short h) {
    return __uint_as_float(((unsigned)(unsigned short)h) << 16);
}

// ---------------- prep: adjacency symmetrize + W transpose to bf16 ----------------
__global__ __launch_bounds__(256) void prep_kernel(
    const float* __restrict__ W, const float* __restrict__ adj,
    const float* __restrict__ adj2, float* __restrict__ wsf)
{
    const int t = threadIdx.x;            // 0..255
    short* wbt = (short*)(wsf + OFF_WBT);
    const int sel = t >> 7, np = t & 127;
    const float* wsrc = W + sel * 16384 + np;   // W[sel][k][np]
    #pragma unroll 8
    for (int k = 0; k < 128; ++k)
        wbt[t * 128 + k] = f2bf(wsrc[k * 128]); // WbfT[col][k]
    // FIX R1: 289 entries > 256 threads -> strided loop (was `if (t<289)`,
    // leaving rows 15,16 and diag[15],diag[16] as 0xAA ws-poison)
    for (int e = t; e < 289; e += 256) {
        int i = e / 17, j = e % 17;
        float v = 0.5f * (adj[i*17+j] + adj2[i*17+j] + adj[j*17+i] + adj2[j*17+i]);
        if (i == j) { wsf[OFF_DIAG + i] = v; v = 0.f; }
        wsf[OFF_OFFSYM + i*17 + j] = v;
    }
}

// ---------------- conv: 4 batches (68 rows) per block, MFMA bf16 ----------------
__global__ __launch_bounds__(512, 4) void conv_kernel(
    const float* __restrict__ x, const float* __restrict__ M,
    const float* __restrict__ bias, float* __restrict__ out,
    float* __restrict__ wsf)
{
    __shared__ short A_lds[80][136];   // bf16 x-tile, rows 68..79 zero pad, +8 col pad
    __shared__ short hh[68][260];      // bf16 h0 (cols 0..127) | h1 (cols 128..255)
    __shared__ float red[512], red2[512];

    const int tid = threadIdx.x;
    const int w = tid >> 6, l = tid & 63, c = l & 15, g = l >> 4;

    // ---- stage x[blk*68 .. +68) f32 -> bf16 LDS ----
    const float4* xsrc = (const float4*)(x + (size_t)blockIdx.x * (68 * 128));
    #pragma unroll
    for (int it = 0; it < 5; ++it) {
        int f = tid + it * 512;
        if (f < 2176) {                    // 68*128/4
            float4 v = xsrc[f];
            int r = f >> 5, k0 = (f & 31) << 2;
            bf16x4 p;
            p[0] = f2bf(v.x); p[1] = f2bf(v.y); p[2] = f2bf(v.z); p[3] = f2bf(v.w);
            *(bf16x4*)&A_lds[r][k0] = p;
        }
    }
    if (tid < 408) {                       // zero pad rows 68..79 (12*272B / 8)
        bf16x4 z = {0, 0, 0, 0};
        ((bf16x4*)&A_lds[68][0])[tid] = z;
    }
    __syncthreads();

    // ---- K-loop: C[80 x 256] : wave w owns cols w*32..w*32+31 ----
    const short* wbt = (const short*)(wsf + OFF_WBT);
    const int cb = w * 32;
    f32x4 acc[5][2];
    #pragma unroll
    for (int mt = 0; mt < 5; ++mt)
        #pragma unroll
        for (int nt = 0; nt < 2; ++nt)
            acc[mt][nt] = (f32x4){0.f, 0.f, 0.f, 0.f};

    #pragma unroll
    for (int ks = 0; ks < 4; ++ks) {
        // B frags: lane reads WbfT[col][k0..k0+7] (16B contiguous)
        bf16x8 bf0 = *(const bf16x8*)(wbt + (cb + c) * 128      + ks * 32 + g * 8);
        bf16x8 bf1 = *(const bf16x8*)(wbt + (cb + 16 + c) * 128 + ks * 32 + g * 8);
        #pragma unroll
        for (int mt = 0; mt < 5; ++mt) {
            bf16x8 af = *(const bf16x8*)&A_lds[mt * 16 + c][ks * 32 + g * 8];
            acc[mt][0] = __builtin_amdgcn_mfma_f32_16x16x32_bf16(af, bf0, acc[mt][0], 0, 0, 0);
            acc[mt][1] = __builtin_amdgcn_mfma_f32_16x16x32_bf16(af, bf1, acc[mt][1], 0, 0, 0);
        }
    }

    // ---- acc -> hh (bf16). D layout: row=(lane>>4)*4+reg, col=lane&15 ----
    #pragma unroll
    for (int mt = 0; mt < 5; ++mt) {
        int row0 = mt * 16 + g * 4;
        #pragma unroll
        for (int nt = 0; nt < 2; ++nt) {
            #pragma unroll
            for (int r = 0; r < 4; ++r) {
                int row = row0 + r;
                if (row < 68) hh[row][cb + nt * 16 + c] = f2bf(acc[mt][nt][r]);
            }
        }
    }
    __syncthreads();

    // ---- mixing: one thread per (bb, o); off/diag via uniform (scalar) loads ----
    const int bb = tid >> 7;               // 0..3
    const int o  = tid & 127;
    const float* offp  = wsf + OFF_OFFSYM;
    const float* diagp = wsf + OFF_DIAG;
    const int rbase = bb * 17;
    const float bv = bias[o];

    float vout[17];
    #pragma unroll
    for (int i = 0; i < 17; ++i) {
        float h0v = bf2f(hh[rbase + i][o]);
        vout[i] = fmaf(diagp[i] * M[i * 128 + o], h0v, bv);
    }
    #pragma unroll
    for (int j = 0; j < 17; ++j) {
        float h1v = bf2f(hh[rbase + j][128 + o]) * M[j * 128 + o];
        #pragma unroll
        for (int i = 0; i < 17; ++i)
            vout[i] = fmaf(offp[i * 17 + j], h1v, vout[i]);
    }

    float s = 0.f, s2 = 0.f;
    float* op = out + ((size_t)blockIdx.x * 68 + rbase) * 128 + o;
    #pragma unroll
    for (int i = 0; i < 17; ++i) {
        float v = vout[i];
        op[i * 128] = v;
        s += v; s2 = fmaf(v, v, s2);
    }

    // ---- BN partials -> replicated slots ----
    red[tid] = s; red2[tid] = s2;
    __syncthreads();
    if (tid < 128) {
        float ts = red[tid] + red[tid + 128] + red[tid + 256] + red[tid + 384];
        float t2 = red2[tid] + red2[tid + 128] + red2[tid + 256] + red2[tid + 384];
        float* slot = wsf + OFF_PART + ((blockIdx.x & (NSLOT - 1)) << 8);
        atomicAdd(slot + tid, ts);
        atomicAdd(slot + 128 + tid, t2);
    }
}

// ---------------- BN stats reduce ----------------
__global__ __launch_bounds__(256) void bn_reduce_kernel(
    const float* __restrict__ part, const float* __restrict__ gamma,
    const float* __restrict__ beta, float* __restrict__ stats)
{
    const int t = threadIdx.x;             // 0..255
    float s = 0.f;
    #pragma unroll 8
    for (int i = 0; i < NSLOT; ++i) s += part[i * 256 + t];
    __shared__ float tot[256];
    tot[t] = s;
    __syncthreads();
    if (t < 128) {
        const float n = 139264.f;          // 8192*17
        float mean = tot[t] / n;
        float var  = tot[t + 128] / n - mean * mean;
        var = fmaxf(var, 0.f);
        float inv = rsqrtf(var + 1e-5f);
        float sc = gamma[t] * inv;
        stats[t] = sc;
        stats[t + 128] = beta[t] - mean * sc;
    }
}

// ---------------- BN apply + relu (in-place on out) ----------------
__global__ __launch_bounds__(256) void apply_kernel(
    float* __restrict__ out, const float* __restrict__ stats, int n4)
{
    const int tid = blockIdx.x * 256 + threadIdx.x;
    const int c0 = (tid << 2) & 127;       // stride (2048*256*4) % 128 == 0 -> fixed channels
    const float sc0 = stats[c0],     sc1 = stats[c0 + 1],
                sc2 = stats[c0 + 2], sc3 = stats[c0 + 3];
    const float sh0 = stats[128 + c0],     sh1 = stats[128 + c0 + 1],
                sh2 = stats[128 + c0 + 2], sh3 = stats[128 + c0 + 3];
    float4* o4 = (float4*)out;
    for (int q = tid; q < n4; q += 2048 * 256) {
        float4 v = o4[q];
        v.x = fmaxf(fmaf(v.x, sc0, sh0), 0.f);
        v.y = fmaxf(fmaf(v.y, sc1, sh1), 0.f);
        v.z = fmaxf(fmaf(v.z, sc2, sh2), 0.f);
        v.w = fmaxf(fmaf(v.w, sc3, sh3), 0.f);
        o4[q] = v;
    }
}

extern "C" void kernel_launch(void* const* d_in, const int* in_sizes, int n_in,
                              void* d_out, int out_size, void* d_ws, size_t ws_size,
                              hipStream_t stream) {
    (void)in_sizes; (void)n_in; (void)out_size; (void)ws_size;
    const float* x     = (const float*)d_in[0];
    const float* W     = (const float*)d_in[1];
    const float* M     = (const float*)d_in[2];
    const float* adj   = (const float*)d_in[3];
    const float* adj2  = (const float*)d_in[4];
    const float* bias  = (const float*)d_in[5];
    const float* gamma = (const float*)d_in[6];
    const float* beta  = (const float*)d_in[7];
    float* out = (float*)d_out;
    float* wsf = (float*)d_ws;

    hipMemsetAsync(d_ws, 0, NSLOT * 256 * sizeof(float), stream);   // BN partial slots
    prep_kernel<<<1, 256, 0, stream>>>(W, adj, adj2, wsf);
    conv_kernel<<<2048, 512, 0, stream>>>(x, M, bias, out, wsf);
    bn_reduce_kernel<<<1, 256, 0, stream>>>(wsf + OFF_PART, gamma, beta, wsf + OFF_STATS);
    apply_kernel<<<2048, 256, 0, stream>>>(out, wsf + OFF_STATS, 4456448);
}